// Round 2
// baseline (2313.304 us; speedup 1.0000x reference)
//
#include <hip/hip_runtime.h>
#include <hip/hip_bf16.h>

typedef __hip_bfloat16 bf16;

static constexpr int kN   = 4096;    // nodes
static constexpr int kND  = 256;     // hidden
static constexpr int kEL  = 131072;  // local edges
static constexpr int kED  = 32;      // edge dim
static constexpr int kELG = 262144;  // line-graph edges
static constexpr int kNPB = 128;     // nodes per block
static constexpr int kL   = 2;
static constexpr float kScaleN = 0.17677669529663687f; // 1/sqrt(32)

__device__ __forceinline__ float ldf(const void* p, size_t i, int isbf){
    return isbf ? __bfloat162float(((const bf16*)p)[i]) : ((const float*)p)[i];
}
__device__ __forceinline__ unsigned f2o(float f){
    unsigned u = __float_as_uint(f);
    return (u & 0x80000000u) ? ~u : (u | 0x80000000u);
}
__device__ __forceinline__ float o2f(unsigned m){
    return __uint_as_float((m & 0x80000000u) ? (m & 0x7fffffffu) : ~m);
}

// ---------------- dtype detection ----------------
__global__ void detect_k(const unsigned short* __restrict__ xin, int* __restrict__ flag){
    if (threadIdx.x == 0 && blockIdx.x == 0) {
        int plausible = 0;
        for (int i = 0; i < 128; ++i) {
            unsigned short u = xin[i];
            int e = (u >> 7) & 0xFF;
            if (e == 0 || (e >= 110 && e <= 140)) ++plausible;
        }
        *flag = (plausible >= 102) ? 1 : 0;   // bf16 if >=80% plausible exponents
    }
}

// ---------------- casts / init ----------------
__global__ void cast_x_k(const void* __restrict__ xin, float* __restrict__ xout,
                         const int* __restrict__ flag, int n){
    const int isbf = *flag;
    int g = blockIdx.x*256 + threadIdx.x;
    if (g < n) xout[g] = ldf(xin, g, isbf);
}
__global__ void init_lg_k(const void* __restrict__ rel, const int* __restrict__ feat,
                          float* __restrict__ lg, const int* __restrict__ flag){
    const int isbf = *flag;
    int g = blockIdx.x*256 + threadIdx.x;   // over kEL*32
    int e = g >> 5, d = g & 31;
    lg[g] = ldf(rel, (size_t)feat[e]*kED + d, isbf);
}

// ---------------- generic tiled GEMM ----------------
// C[M,N] = (idx? A[idx[row]] : A[row]) @ W[woff..][K,N] (+bias[boff..]) (+Res) (+ACC) (RELU)
// flags: 1 = ACC, 2 = RELU, 4 = has-bias
template<int BN>
__global__ __launch_bounds__(256) void gemm_k(
    const float* __restrict__ A, const int* __restrict__ idx,
    const void* __restrict__ W, size_t woff,
    const void* __restrict__ bias, size_t boff,
    const float* __restrict__ Res, float* __restrict__ C,
    const int* __restrict__ flag, int M, int N, int K, int flags)
{
    constexpr int BM = 64, BK = 16;
    constexpr int TM = 4, TN = BN/16;
    __shared__ float As[BK][BM+1];
    __shared__ float Ws[BK][BN];
    const int isbf = *flag;
    const int tid = threadIdx.x;
    const int tx = tid & 15, ty = tid >> 4;
    const int m0 = blockIdx.y * BM, n0 = blockIdx.x * BN;
    float acc[TM][TN];
    #pragma unroll
    for (int i=0;i<TM;i++)
        #pragma unroll
        for (int j=0;j<TN;j++) acc[i][j] = 0.f;

    for (int k0 = 0; k0 < K; k0 += BK) {
        #pragma unroll
        for (int t = 0; t < (BM*BK)/256; ++t) {
            int lin = tid + t*256;
            int r = lin / BK, c = lin % BK;
            int row = m0 + r;                       // M always multiple of 64
            int arow = idx ? idx[row] : row;
            As[c][r] = A[(size_t)arow * K + k0 + c];
        }
        #pragma unroll
        for (int t = 0; t < (BK*BN)/256; ++t) {
            int lin = tid + t*256;
            int n = lin % BN, c = lin / BN;
            int col = n0 + n;
            Ws[c][n] = (col < N) ? ldf(W, woff + (size_t)(k0 + c) * N + col, isbf) : 0.f;
        }
        __syncthreads();
        #pragma unroll
        for (int kk = 0; kk < BK; ++kk) {
            float a[TM], b[TN];
            #pragma unroll
            for (int i=0;i<TM;i++) a[i] = As[kk][ty*TM+i];
            #pragma unroll
            for (int j=0;j<TN;j++) b[j] = Ws[kk][tx*TN+j];
            #pragma unroll
            for (int i=0;i<TM;i++)
                #pragma unroll
                for (int j=0;j<TN;j++)
                    acc[i][j] += a[i]*b[j];
        }
        __syncthreads();
    }
    const bool do_acc  = flags & 1;
    const bool do_relu = flags & 2;
    const bool has_b   = flags & 4;
    #pragma unroll
    for (int i=0;i<TM;i++) {
        int row = m0 + ty*TM + i;
        #pragma unroll
        for (int j=0;j<TN;j++) {
            int col = n0 + tx*TN + j;
            if (col < N) {
                float v = acc[i][j];
                if (has_b)  v += ldf(bias, boff + col, isbf);
                if (Res)    v += Res[(size_t)row*N + col];
                if (do_acc) v += C[(size_t)row*N + col];
                if (do_relu) v = fmaxf(v, 0.f);
                C[(size_t)row*N + col] = v;
            }
        }
    }
}

// ---------------- LayerNorm: out = LN(a (+ b)) * g[goff..] + beta[goff..] ----------------
__global__ __launch_bounds__(64) void ln_k(
    const float* __restrict__ a, const float* __restrict__ b,
    const void* __restrict__ g, const void* __restrict__ be, size_t goff,
    float* __restrict__ out, const int* __restrict__ flag, int D)
{
    const int isbf = *flag;
    const int row = blockIdx.x;
    const int t = threadIdx.x;
    float v[4];
    int cnt = 0;
    float s = 0.f;
    for (int i = t; i < D; i += 64) {
        float x = a[(size_t)row*D + i];
        if (b) x += b[(size_t)row*D + i];
        v[cnt++] = x; s += x;
    }
    #pragma unroll
    for (int off = 32; off > 0; off >>= 1) s += __shfl_down(s, off);
    s = __shfl(s, 0);
    const float mean = s / D;
    float qq = 0.f;
    for (int c2 = 0; c2 < cnt; ++c2) { float d = v[c2]-mean; qq += d*d; }
    #pragma unroll
    for (int off = 32; off > 0; off >>= 1) qq += __shfl_down(qq, off);
    qq = __shfl(qq, 0);
    const float inv = rsqrtf(fmaxf(qq, 0.f) / D + 1e-5f);
    cnt = 0;
    for (int i = t; i < D; i += 64)
        out[(size_t)row*D + i] = (v[cnt++] - mean)*inv*ldf(g, goff + i, isbf) + ldf(be, goff + i, isbf);
}

// ---------------- full-graph attention (block-diagonal complete, heads 0..3) ----------------
__global__ __launch_bounds__(128) void full_attn_k(
    const float* __restrict__ q, const float* __restrict__ k, const float* __restrict__ v,
    const void* __restrict__ rel, const int* __restrict__ feat, float* __restrict__ o,
    const int* __restrict__ flag)
{
    __shared__ float ks[kNPB][kED];
    __shared__ float vs[kNPB][kED];
    __shared__ float rs[128][kED+1];
    const int isbf = *flag;
    const int b = blockIdx.x >> 2, h = blockIdx.x & 3;
    const int t = threadIdx.x;         // t == local dst
    for (int i = t; i < 128*kED; i += 128) rs[i>>5][i&31] = ldf(rel, i, isbf);
    for (int i = t; i < kNPB*kED; i += 128) {
        int r = i >> 5, d = i & 31;
        size_t base = ((size_t)(b*kNPB + r))*kND + h*kED;
        ks[r][d] = k[base + d];
        vs[r][d] = v[base + d];
    }
    __syncthreads();
    float qr[kED];
    { size_t base = ((size_t)(b*kNPB + t))*kND + h*kED;
      #pragma unroll
      for (int d=0; d<kED; ++d) qr[d] = q[base + d]; }
    const int* fp = feat + (size_t)b*kNPB*kNPB + t;
    float m = -1e30f, l = 0.f;
    float acc[kED];
    #pragma unroll
    for (int d=0; d<kED; ++d) acc[d] = 0.f;
    int f = fp[0];
    for (int s = 0; s < kNPB; ++s) {
        int fn = (s+1 < kNPB) ? fp[(s+1)*kNPB] : 0;
        float sc = 0.f;
        #pragma unroll
        for (int d=0; d<kED; ++d) sc += (ks[s][d] + rs[f][d]) * qr[d];
        sc *= kScaleN;
        float mn = fmaxf(m, sc);
        float c0 = __expf(fminf(m - mn, 0.f));
        float pp = __expf(fminf(sc - mn, 0.f));
        l = l*c0 + pp;
        #pragma unroll
        for (int d=0; d<kED; ++d) acc[d] = acc[d]*c0 + pp*(vs[s][d] + rs[f][d]);
        m = mn;
        f = fn;
    }
    const float inv = 1.f / fmaxf(l, 1e-30f);
    size_t base = ((size_t)(b*kNPB + t))*kND + h*kED;
    #pragma unroll
    for (int d=0; d<kED; ++d) o[base + d] = acc[d]*inv;
}

// ---------------- local-graph scatter attention (heads 4..7) ----------------
__global__ __launch_bounds__(256) void loc_score_k(
    const float* __restrict__ q, const float* __restrict__ k, const float* __restrict__ lg,
    const int* __restrict__ gsrc, const int* __restrict__ gdst,
    float* __restrict__ sc, unsigned* __restrict__ smax)
{
    int g = blockIdx.x*256 + threadIdx.x;   // kEL*4
    int e = g >> 2, h = g & 3;
    int s = gsrc[e], d2 = gdst[e];
    const float* kp = k + (size_t)s*kND + (4+h)*kED;
    const float* qp = q + (size_t)d2*kND + (4+h)*kED;
    const float* ep = lg + (size_t)e*kED;
    float a = 0.f;
    #pragma unroll
    for (int d=0; d<kED; ++d) a += (kp[d] + ep[d]) * qp[d];
    a *= kScaleN;
    sc[g] = a;
    atomicMax(&smax[d2*4 + h], f2o(a));
}
__global__ __launch_bounds__(256) void loc_exp_k(
    const int* __restrict__ gdst, float* __restrict__ sc,
    const unsigned* __restrict__ smax, float* __restrict__ den)
{
    int g = blockIdx.x*256 + threadIdx.x;   // kEL*4
    int e = g >> 2, h = g & 3;
    int d2 = gdst[e];
    float ex = __expf(fminf(sc[g] - o2f(smax[d2*4 + h]), 0.f));
    sc[g] = ex;
    atomicAdd(&den[d2*4 + h], ex);
}
__global__ __launch_bounds__(256) void loc_out_k(
    const float* __restrict__ v, const float* __restrict__ lg,
    const int* __restrict__ gsrc, const int* __restrict__ gdst,
    const float* __restrict__ sc, const float* __restrict__ den,
    float* __restrict__ o)
{
    int g = blockIdx.x*256 + threadIdx.x;   // kEL*128
    int d = g & 31, h = (g>>5)&3, e = g >> 7;
    int s = gsrc[e], d2 = gdst[e];
    float alpha = sc[e*4+h] / fmaxf(den[d2*4+h], 1e-30f);
    float val = alpha * (v[(size_t)s*kND + (4+h)*kED + d] + lg[(size_t)e*kED + d]);
    atomicAdd(&o[(size_t)d2*kND + (4+h)*kED + d], val);
}

// ---------------- line-graph scatter attention (8 heads, d=4, no e-bias) ----------------
__global__ __launch_bounds__(256) void lgs_score_k(
    const float* __restrict__ eq, const float* __restrict__ ek,
    const int* __restrict__ lsrc, const int* __restrict__ ldst,
    float* __restrict__ sc, unsigned* __restrict__ smax)
{
    int g = blockIdx.x*256 + threadIdx.x;   // kELG*8
    int e = g >> 3, h = g & 7;
    int s = lsrc[e], d2 = ldst[e];
    const float* kp = ek + (size_t)s*kED + h*4;
    const float* qp = eq + (size_t)d2*kED + h*4;
    float a = 0.f;
    #pragma unroll
    for (int d=0; d<4; ++d) a += kp[d]*qp[d];
    a *= 0.5f;                                // 1/sqrt(4)
    sc[g] = a;
    atomicMax(&smax[d2*8 + h], f2o(a));
}
__global__ __launch_bounds__(256) void lgs_exp_k(
    const int* __restrict__ ldst, float* __restrict__ sc,
    const unsigned* __restrict__ smax, float* __restrict__ den)
{
    int g = blockIdx.x*256 + threadIdx.x;   // kELG*8
    int e = g >> 3, h = g & 7;
    int d2 = ldst[e];
    float ex = __expf(fminf(sc[g] - o2f(smax[d2*8 + h]), 0.f));
    sc[g] = ex;
    atomicAdd(&den[d2*8 + h], ex);
}
__global__ __launch_bounds__(256) void lgs_out_k(
    const float* __restrict__ ev,
    const int* __restrict__ lsrc, const int* __restrict__ ldst,
    const float* __restrict__ sc, const float* __restrict__ den,
    float* __restrict__ ow)
{
    int g = blockIdx.x*256 + threadIdx.x;   // kELG*32
    int d = g & 3, h = (g>>2)&7, e = g >> 5;
    int s = lsrc[e], d2 = ldst[e];
    float alpha = sc[e*8+h] / fmaxf(den[d2*8+h], 1e-30f);
    atomicAdd(&ow[(size_t)d2*kED + h*4 + d], alpha * ev[(size_t)s*kED + h*4 + d]);
}

// ---------------- output: concat(x, lg) -> out (dtype per flag) ----------------
__global__ void out_k(const float* __restrict__ xf, const float* __restrict__ lgf,
                      void* __restrict__ out, const int* __restrict__ flag){
    const int isbf = *flag;
    int g = blockIdx.x*256 + threadIdx.x;   // kN*kND + kEL*kED
    float v = (g < kN*kND) ? xf[g] : lgf[g - kN*kND];
    if (isbf) ((bf16*)out)[g] = __float2bfloat16(v);
    else      ((float*)out)[g] = v;
}

// ---------------- host helpers ----------------
static inline void gemm64(const float* A, const int* idx, const void* W, size_t woff,
                          const void* bias, size_t boff, const float* Res, float* C,
                          const int* flag, int M, int N, int K, int flags, hipStream_t s){
    dim3 grid((N+63)/64, M/64);
    gemm_k<64><<<grid, 256, 0, s>>>(A, idx, W, woff, bias, boff, Res, C, flag, M, N, K, flags);
}
static inline void gemm32(const float* A, const int* idx, const void* W, size_t woff,
                          const void* bias, size_t boff, const float* Res, float* C,
                          const int* flag, int M, int N, int K, int flags, hipStream_t s){
    dim3 grid((N+31)/32, M/64);
    gemm_k<32><<<grid, 256, 0, s>>>(A, idx, W, woff, bias, boff, Res, C, flag, M, N, K, flags);
}

extern "C" void kernel_launch(void* const* d_in, const int* in_sizes, int n_in,
                              void* d_out, int out_size, void* d_ws, size_t ws_size,
                              hipStream_t stream) {
    const void* x_in      = d_in[0];
    const void* rel       = d_in[1];
    const int* g_src      = (const int*)d_in[4];
    const int* g_dst      = (const int*)d_in[5];
    const int* lg_src     = (const int*)d_in[6];
    const int* lg_dst     = (const int*)d_in[7];
    const int* edge_feat  = (const int*)d_in[8];
    const int* full_feat  = (const int*)d_in[9];
    const void* n_Wq   = d_in[10];
    const void* n_bq   = d_in[11];
    const void* n_Wk   = d_in[12];
    const void* n_bk   = d_in[13];
    const void* n_Wv   = d_in[14];
    const void* n_bv   = d_in[15];
    const void* n_Wo   = d_in[16];
    const void* n_bo   = d_in[17];
    const void* n_lng  = d_in[18];
    const void* n_lnb  = d_in[19];
    const void* n_fW1  = d_in[20];
    const void* n_fb1  = d_in[21];
    const void* n_fW2  = d_in[22];
    const void* n_fb2  = d_in[23];
    const void* n_flng = d_in[24];
    const void* n_flnb = d_in[25];
    const void* e_Wsrc = d_in[26];
    const void* e_Wdst = d_in[27];
    const void* e_Wq   = d_in[28];
    const void* e_bq   = d_in[29];
    const void* e_Wk   = d_in[30];
    const void* e_Wv   = d_in[31];
    const void* e_Wo   = d_in[32];
    const void* e_bo   = d_in[33];
    const void* e_lng  = d_in[34];
    const void* e_lnb  = d_in[35];
    const void* e_fW1  = d_in[36];
    const void* e_fb1  = d_in[37];
    const void* e_fW2  = d_in[38];
    const void* e_fb2  = d_in[39];
    const void* e_flng = d_in[40];
    const void* e_flnb = d_in[41];

    // ---- workspace carve-up (fp32), lifetime-based aliasing ----
    float* p = (float*)d_ws;
    size_t off = 0;
    auto AL = [&](size_t n){ float* r = p + off; off += n; return r; };
    int* flagp = (int*)AL(64);
    float* xA   = AL((size_t)kN*kND);
    float* xB   = AL((size_t)kN*kND);
    float* xM   = AL((size_t)kN*kND);
    float* qb   = AL((size_t)kN*kND);
    float* kb   = AL((size_t)kN*kND);
    float* vb   = AL((size_t)kN*kND);
    float* ob   = AL((size_t)kN*kND);
    float* tN   = AL((size_t)kN*kND);
    float* lgA  = AL((size_t)kEL*kED);
    float* lgB  = AL((size_t)kEL*kED);
    float* lgM  = AL((size_t)kEL*kED);
    float* mixed= AL((size_t)kEL*kED);   // aliases node-FFN hidden [4096,1024]
    float* eqb  = AL((size_t)kEL*kED);
    float* ekb  = AL((size_t)kEL*kED);
    float* evb  = AL((size_t)kEL*kED);
    float* owb  = AL((size_t)kEL*kED);
    float* tE   = AL((size_t)kEL*kED);
    float* scL  = AL((size_t)kEL*4);
    unsigned* smL = (unsigned*)AL((size_t)kN*4);
    float* dnL  = AL((size_t)kN*4);
    float* scG  = AL((size_t)kELG*8);
    unsigned* smG = (unsigned*)AL((size_t)kEL*8);
    float* dnG  = AL((size_t)kEL*8);
    float* nh  = mixed;   // node FFN hidden [4096,1024]
    float* ehb = eqb;     // edge FFN hidden [131072,128] spans eqb..owb
    if (ws_size < off * sizeof(float)) return;

    detect_k<<<1, 64, 0, stream>>>((const unsigned short*)x_in, flagp);
    cast_x_k<<<(kN*kND)/256, 256, 0, stream>>>(x_in, xA, flagp, kN*kND);
    init_lg_k<<<(kEL*kED)/256, 256, 0, stream>>>(rel, edge_feat, lgA, flagp);

    float* xc = xA;  float* xn = xB;
    float* lgc = lgA; float* lgn = lgB;

    for (int i = 0; i < kL; ++i) {
        const size_t oW   = (size_t)i*kND*kND;
        const size_t ofW1 = (size_t)i*kND*1024;
        const size_t ofW2 = (size_t)i*1024*kND;
        const size_t oWs  = (size_t)i*kND*kED;
        const size_t oeW  = (size_t)i*kED*kED;
        const size_t oefW1= (size_t)i*kED*128;
        const size_t oefW2= (size_t)i*128*kED;
        const size_t o256 = (size_t)i*kND;
        const size_t o1024= (size_t)i*1024;
        const size_t o32  = (size_t)i*kED;
        const size_t o128 = (size_t)i*128;

        // ===== node update =====
        gemm64(xc, nullptr, n_Wq, oW, n_bq, o256, nullptr, qb, flagp, kN, kND, kND, 4, stream);
        gemm64(xc, nullptr, n_Wk, oW, n_bk, o256, nullptr, kb, flagp, kN, kND, kND, 4, stream);
        gemm64(xc, nullptr, n_Wv, oW, n_bv, o256, nullptr, vb, flagp, kN, kND, kND, 4, stream);
        hipMemsetAsync(ob,  0, (size_t)kN*kND*sizeof(float), stream);
        hipMemsetAsync(smL, 0, (size_t)kN*4*sizeof(unsigned), stream);
        hipMemsetAsync(dnL, 0, (size_t)kN*4*sizeof(float), stream);
        full_attn_k<<<128, 128, 0, stream>>>(qb, kb, vb, rel, full_feat, ob, flagp);
        loc_score_k<<<(kEL*4)/256, 256, 0, stream>>>(qb, kb, lgc, g_src, g_dst, scL, smL);
        loc_exp_k  <<<(kEL*4)/256, 256, 0, stream>>>(g_dst, scL, smL, dnL);
        loc_out_k  <<<(kEL*128)/256, 256, 0, stream>>>(vb, lgc, g_src, g_dst, scL, dnL, ob);
        gemm64(ob, nullptr, n_Wo, oW, n_bo, o256, nullptr, tN, flagp, kN, kND, kND, 4, stream);
        ln_k<<<kN, 64, 0, stream>>>(xc, tN, n_lng, n_lnb, o256, xM, flagp, kND);
        gemm64(xM, nullptr, n_fW1, ofW1, n_fb1, o1024, nullptr, nh, flagp, kN, 1024, kND, 4|2, stream);
        gemm64(nh, nullptr, n_fW2, ofW2, n_fb2, o256, nullptr, tN, flagp, kN, kND, 1024, 4, stream);
        ln_k<<<kN, 64, 0, stream>>>(xM, tN, n_flng, n_flnb, o256, xn, flagp, kND);

        // ===== edge update (uses PRE-update xc, lgc) =====
        gemm32(xc, g_src, e_Wsrc, oWs, nullptr, 0, lgc, mixed, flagp, kEL, kED, kND, 0, stream);
        gemm32(xc, g_dst, e_Wdst, oWs, nullptr, 0, nullptr, mixed, flagp, kEL, kED, kND, 1, stream);
        gemm32(mixed, nullptr, e_Wq, oeW, e_bq, o32, nullptr, eqb, flagp, kEL, kED, kED, 4, stream);
        gemm32(mixed, nullptr, e_Wk, oeW, nullptr, 0, nullptr, ekb, flagp, kEL, kED, kED, 0, stream);
        gemm32(mixed, nullptr, e_Wv, oeW, nullptr, 0, nullptr, evb, flagp, kEL, kED, kED, 0, stream);
        hipMemsetAsync(owb, 0, (size_t)kEL*kED*sizeof(float), stream);
        hipMemsetAsync(smG, 0, (size_t)kEL*8*sizeof(unsigned), stream);
        hipMemsetAsync(dnG, 0, (size_t)kEL*8*sizeof(float), stream);
        lgs_score_k<<<(kELG*8)/256, 256, 0, stream>>>(eqb, ekb, lg_src, lg_dst, scG, smG);
        lgs_exp_k  <<<(kELG*8)/256, 256, 0, stream>>>(lg_dst, scG, smG, dnG);
        lgs_out_k  <<<(kELG*32)/256, 256, 0, stream>>>(evb, lg_src, lg_dst, scG, dnG, owb);
        gemm32(owb, nullptr, e_Wo, oeW, e_bo, o32, nullptr, tE, flagp, kEL, kED, kED, 4, stream);
        ln_k<<<kEL, 64, 0, stream>>>(lgc, tE, e_lng, e_lnb, o32, lgM, flagp, kED);
        gemm64(lgM, nullptr, e_fW1, oefW1, e_fb1, o128, nullptr, ehb, flagp, kEL, 128, kED, 4|2, stream);
        gemm32(ehb, nullptr, e_fW2, oefW2, e_fb2, o32, nullptr, tE, flagp, kEL, kED, 128, 4, stream);
        ln_k<<<kEL, 64, 0, stream>>>(lgM, tE, e_flng, e_flnb, o32, lgn, flagp, kED);

        { float* t = xc; xc = xn; xn = t; }
        { float* t = lgc; lgc = lgn; lgn = t; }
    }

    out_k<<<(kN*kND + kEL*kED)/256, 256, 0, stream>>>(xc, lgc, d_out, flagp);
}

// Round 3
// 1456.394 us; speedup vs baseline: 1.5884x; 1.5884x over previous
//
#include <hip/hip_runtime.h>
#include <hip/hip_bf16.h>

typedef __hip_bfloat16 bf16;

static constexpr int kN   = 4096;    // nodes
static constexpr int kND  = 256;     // hidden
static constexpr int kEL  = 131072;  // local edges
static constexpr int kED  = 32;      // edge dim
static constexpr int kELG = 262144;  // line-graph edges
static constexpr int kNPB = 128;     // nodes per block
static constexpr int kL   = 2;
static constexpr float kScaleN = 0.17677669529663687f; // 1/sqrt(32)

__device__ __forceinline__ float ldf(const void* p, size_t i, int isbf){
    return isbf ? __bfloat162float(((const bf16*)p)[i]) : ((const float*)p)[i];
}
__device__ __forceinline__ unsigned f2o(float f){
    unsigned u = __float_as_uint(f);
    return (u & 0x80000000u) ? ~u : (u | 0x80000000u);
}
__device__ __forceinline__ float o2f(unsigned m){
    return __uint_as_float((m & 0x80000000u) ? (m & 0x7fffffffu) : ~m);
}

// ---------------- dtype detection ----------------
__global__ void detect_k(const unsigned short* __restrict__ xin, int* __restrict__ flag){
    if (threadIdx.x == 0 && blockIdx.x == 0) {
        int plausible = 0;
        for (int i = 0; i < 128; ++i) {
            unsigned short u = xin[i];
            int e = (u >> 7) & 0xFF;
            if (e == 0 || (e >= 110 && e <= 140)) ++plausible;
        }
        *flag = (plausible >= 102) ? 1 : 0;
    }
}

// ---------------- casts / init ----------------
__global__ void cast_x_k(const void* __restrict__ xin, float* __restrict__ xout,
                         const int* __restrict__ flag, int n){
    const int isbf = *flag;
    int g = blockIdx.x*256 + threadIdx.x;
    if (g < n) xout[g] = ldf(xin, g, isbf);
}
__global__ void init_lg_k(const void* __restrict__ rel, const int* __restrict__ feat,
                          float* __restrict__ lg, const int* __restrict__ flag){
    const int isbf = *flag;
    int g = blockIdx.x*256 + threadIdx.x;   // over kEL*32
    int e = g >> 5, d = g & 31;
    lg[g] = ldf(rel, (size_t)feat[e]*kED + d, isbf);
}

// ---------------- generic tiled GEMM (register-prefetch pipelined) ----------------
// C[M,N] = (idx? A[idx[row]] : A[row]) @ W[woff..][K,N] (+bias[boff..]) (+Res) (+ACC) (RELU)
// flags: 1 = ACC, 2 = RELU, 4 = has-bias
template<int BN>
__global__ __launch_bounds__(256) void gemm_k(
    const float* __restrict__ A, const int* __restrict__ idx,
    const void* __restrict__ W, size_t woff,
    const void* __restrict__ bias, size_t boff,
    const float* __restrict__ Res, float* __restrict__ C,
    const int* __restrict__ flag, int M, int N, int K, int flags)
{
    constexpr int BM = 64, BK = 16;
    constexpr int TM = 4, TN = BN/16;
    constexpr int NA = 4;            // A elems per thread per tile
    constexpr int NW = BK*BN/256;    // W elems per thread per tile
    __shared__ float As[BK][BM+4];   // +4 pad keeps 16B alignment & breaks conflicts
    __shared__ float Ws[BK][BN];
    const int isbf = *flag;
    const int tid = threadIdx.x;
    const int tx = tid & 15, ty = tid >> 4;
    const int m0 = blockIdx.y * BM, n0 = blockIdx.x * BN;

    int arow[NA], acol[NA];
    #pragma unroll
    for (int t = 0; t < NA; ++t) {
        int lin = tid + t*256;
        int r = lin >> 4, c = lin & 15;
        int row = m0 + r;
        arow[t] = idx ? idx[row] : row;
        acol[t] = c;
    }

    float ra[NA], rw[NW];
    auto loadA = [&](int k0){
        #pragma unroll
        for (int t = 0; t < NA; ++t)
            ra[t] = A[(size_t)arow[t]*K + k0 + acol[t]];
    };
    auto loadW = [&](int k0){
        #pragma unroll
        for (int t = 0; t < NW; ++t) {
            int lin = tid + t*256;
            int n = lin % BN, c = lin / BN;
            int col = n0 + n;
            rw[t] = (col < N) ? ldf(W, woff + (size_t)(k0+c)*N + col, isbf) : 0.f;
        }
    };
    loadA(0); loadW(0);

    float acc[TM][TN];
    #pragma unroll
    for (int i=0;i<TM;i++)
        #pragma unroll
        for (int j=0;j<TN;j++) acc[i][j] = 0.f;

    for (int k0 = 0; k0 < K; k0 += BK) {
        #pragma unroll
        for (int t = 0; t < NA; ++t) {
            int lin = tid + t*256;
            As[lin & 15][lin >> 4] = ra[t];
        }
        #pragma unroll
        for (int t = 0; t < NW; ++t) {
            int lin = tid + t*256;
            Ws[lin / BN][lin % BN] = rw[t];
        }
        __syncthreads();
        if (k0 + BK < K) { loadA(k0 + BK); loadW(k0 + BK); }   // prefetch overlaps compute
        #pragma unroll
        for (int kk = 0; kk < BK; ++kk) {
            float a[TM], b[TN];
            *(float4*)a = *(const float4*)&As[kk][ty*TM];
            if constexpr (TN == 4) {
                *(float4*)b = *(const float4*)&Ws[kk][tx*TN];
            } else {
                b[0] = Ws[kk][tx*TN];
                b[1] = Ws[kk][tx*TN+1];
            }
            #pragma unroll
            for (int i=0;i<TM;i++)
                #pragma unroll
                for (int j=0;j<TN;j++)
                    acc[i][j] += a[i]*b[j];
        }
        __syncthreads();
    }
    const bool do_acc  = flags & 1;
    const bool do_relu = flags & 2;
    const bool has_b   = flags & 4;
    #pragma unroll
    for (int i=0;i<TM;i++) {
        int row = m0 + ty*TM + i;
        #pragma unroll
        for (int j=0;j<TN;j++) {
            int col = n0 + tx*TN + j;
            if (col < N) {
                float v = acc[i][j];
                if (has_b)  v += ldf(bias, boff + col, isbf);
                if (Res)    v += Res[(size_t)row*N + col];
                if (do_acc) v += C[(size_t)row*N + col];
                if (do_relu) v = fmaxf(v, 0.f);
                C[(size_t)row*N + col] = v;
            }
        }
    }
}

// ---------------- fused eq/ek/ev (+gathered mixed) ----------------
// mixed[e] = lg[e] + xs[src[e]] + xd[dst[e]];  eq = mixed@Wq + bq; ek = mixed@Wk; ev = mixed@Wv
__global__ __launch_bounds__(256) void eqkv_k(
    const float* __restrict__ lg, const float* __restrict__ xs, const float* __restrict__ xd,
    const int* __restrict__ gsrc, const int* __restrict__ gdst,
    const void* __restrict__ Wq, const void* __restrict__ Wk, const void* __restrict__ Wv,
    size_t woff, const void* __restrict__ bq, size_t boff,
    float* __restrict__ eq, float* __restrict__ ek, float* __restrict__ ev,
    const int* __restrict__ flag)
{
    const int isbf = *flag;
    __shared__ float mix[64][33];
    __shared__ float wq[32][33], wk[32][33], wv[32][33];
    __shared__ float bqs[32];
    const int t = threadIdx.x;
    const int e0 = blockIdx.x * 64;
    for (int i = t; i < 1024; i += 256) {
        int d = i >> 5, c = i & 31;
        wq[d][c] = ldf(Wq, woff + i, isbf);
        wk[d][c] = ldf(Wk, woff + i, isbf);
        wv[d][c] = ldf(Wv, woff + i, isbf);
    }
    if (t < 32) bqs[t] = ldf(bq, boff + t, isbf);
    const int r = t >> 2, c0 = (t & 3) * 8;
    {
        int e = e0 + r;
        int s = gsrc[e], d2 = gdst[e];
        const float* lp = lg + (size_t)e * 32 + c0;
        const float* sp = xs + (size_t)s * 32 + c0;
        const float* dp = xd + (size_t)d2 * 32 + c0;
        #pragma unroll
        for (int j = 0; j < 8; ++j) mix[r][c0 + j] = lp[j] + sp[j] + dp[j];
    }
    __syncthreads();
    float aq[8], ak[8], av[8];
    #pragma unroll
    for (int j=0;j<8;++j){ aq[j]=bqs[c0+j]; ak[j]=0.f; av[j]=0.f; }
    #pragma unroll
    for (int d = 0; d < 32; ++d) {
        float a = mix[r][d];
        #pragma unroll
        for (int j=0;j<8;++j){
            aq[j] += a * wq[d][c0+j];
            ak[j] += a * wk[d][c0+j];
            av[j] += a * wv[d][c0+j];
        }
    }
    size_t ob = (size_t)(e0 + r) * 32 + c0;
    #pragma unroll
    for (int j=0;j<8;++j){ eq[ob+j]=aq[j]; ek[ob+j]=ak[j]; ev[ob+j]=av[j]; }
}

// ---------------- fused ow@Wo + bias + residual + LayerNorm (edge, D=32) ----------------
__global__ __launch_bounds__(256) void ewo_ln_k(
    const float* __restrict__ ow, const float* __restrict__ res,
    const void* __restrict__ W, size_t woff, const void* __restrict__ bo, size_t boff,
    const void* __restrict__ g, const void* __restrict__ be, size_t goff,
    float* __restrict__ out, const int* __restrict__ flag)
{
    const int isbf = *flag;
    __shared__ float a[64][33];
    __shared__ float w[32][33];
    __shared__ float bs[32];
    const int t = threadIdx.x;
    const int e0 = blockIdx.x * 64;
    for (int i = t; i < 1024; i += 256) w[i>>5][i&31] = ldf(W, woff + i, isbf);
    if (t < 32) bs[t] = ldf(bo, boff + t, isbf);
    const int r = t >> 2, c0 = (t & 3) * 8;
    {
        const float* op = ow + (size_t)(e0 + r) * 32 + c0;
        #pragma unroll
        for (int j = 0; j < 8; ++j) a[r][c0 + j] = op[j];
    }
    __syncthreads();
    float o[8];
    {
        const float* rp = res + (size_t)(e0 + r) * 32 + c0;
        #pragma unroll
        for (int j=0;j<8;++j) o[j] = bs[c0+j] + rp[j];
    }
    #pragma unroll
    for (int d = 0; d < 32; ++d) {
        float av = a[r][d];
        #pragma unroll
        for (int j=0;j<8;++j) o[j] += av * w[d][c0+j];
    }
    float s = 0.f;
    #pragma unroll
    for (int j=0;j<8;++j) s += o[j];
    s += __shfl_xor(s, 1); s += __shfl_xor(s, 2);
    const float mean = s * (1.f/32.f);
    float q = 0.f;
    #pragma unroll
    for (int j=0;j<8;++j){ float d = o[j]-mean; q += d*d; }
    q += __shfl_xor(q, 1); q += __shfl_xor(q, 2);
    const float inv = rsqrtf(q * (1.f/32.f) + 1e-5f);
    float* outp = out + (size_t)(e0 + r) * 32 + c0;
    #pragma unroll
    for (int j=0;j<8;++j)
        outp[j] = (o[j]-mean)*inv*ldf(g, goff + c0 + j, isbf) + ldf(be, goff + c0 + j, isbf);
}

// ---------------- fused edge FFN (32->128 relu ->32) + residual + LayerNorm ----------------
// out = LN(a + relu(a@W1+b1)@W2 + b2) ; 32 rows per block
__global__ __launch_bounds__(256) void effn_ln_k(
    const float* __restrict__ A,
    const void* __restrict__ W1, size_t w1off, const void* __restrict__ b1, size_t b1off,
    const void* __restrict__ W2, size_t w2off, const void* __restrict__ b2, size_t b2off,
    const void* __restrict__ g, const void* __restrict__ be, size_t goff,
    float* __restrict__ out, const int* __restrict__ flag)
{
    const int isbf = *flag;
    __shared__ float a[32][33];
    __shared__ float w1[32][128];
    __shared__ float w2[128][32];
    __shared__ float hid[32][133];   // stride 133: (5r+d)%32 covers all banks on row reads
    __shared__ float b1s[128], b2s[32];
    const int t = threadIdx.x;
    const int e0 = blockIdx.x * 32;
    for (int i = t; i < 4096; i += 256) {
        w1[i>>7][i&127] = ldf(W1, w1off + i, isbf);
        w2[i>>5][i&31]  = ldf(W2, w2off + i, isbf);
    }
    if (t < 128) b1s[t] = ldf(b1, b1off + t, isbf);
    if (t < 32)  b2s[t] = ldf(b2, b2off + t, isbf);
    const int r = t >> 3, l8 = t & 7;
    {   // load a tile: 4 contiguous floats per thread
        int c0 = l8 * 4;
        const float* ap = A + (size_t)(e0 + r) * 32 + c0;
        #pragma unroll
        for (int j = 0; j < 4; ++j) a[r][c0 + j] = ap[j];
    }
    __syncthreads();
    // phase 1: hidden = relu(a@W1+b1) ; thread: row r, cols l8 + 8j (j<16)
    float h[16];
    #pragma unroll
    for (int j=0;j<16;++j) h[j] = b1s[l8 + 8*j];
    #pragma unroll
    for (int d = 0; d < 32; ++d) {
        float av = a[r][d];
        #pragma unroll
        for (int j=0;j<16;++j) h[j] += av * w1[d][l8 + 8*j];
    }
    #pragma unroll
    for (int j=0;j<16;++j) hid[r][l8 + 8*j] = fmaxf(h[j], 0.f);
    __syncthreads();
    // phase 2: out = hidden@W2 + b2 + a (residual); thread: row r, cols l8 + 8j (j<4)
    float o[4];
    #pragma unroll
    for (int j=0;j<4;++j) o[j] = b2s[l8 + 8*j] + a[r][l8 + 8*j];
    #pragma unroll
    for (int d = 0; d < 128; ++d) {
        float hv = hid[r][d];
        #pragma unroll
        for (int j=0;j<4;++j) o[j] += hv * w2[d][l8 + 8*j];
    }
    // LayerNorm over the row (8 lanes x 4 vals)
    float s = o[0]+o[1]+o[2]+o[3];
    s += __shfl_xor(s, 1); s += __shfl_xor(s, 2); s += __shfl_xor(s, 4);
    const float mean = s * (1.f/32.f);
    float q = 0.f;
    #pragma unroll
    for (int j=0;j<4;++j){ float d = o[j]-mean; q += d*d; }
    q += __shfl_xor(q, 1); q += __shfl_xor(q, 2); q += __shfl_xor(q, 4);
    const float inv = rsqrtf(q * (1.f/32.f) + 1e-5f);
    float* outp = out + (size_t)(e0 + r) * 32;
    #pragma unroll
    for (int j=0;j<4;++j) {
        int c = l8 + 8*j;
        outp[c] = (o[j]-mean)*inv*ldf(g, goff + c, isbf) + ldf(be, goff + c, isbf);
    }
}

// ---------------- LayerNorm (node rows, D=256) ----------------
__global__ __launch_bounds__(64) void ln_k(
    const float* __restrict__ a, const float* __restrict__ b,
    const void* __restrict__ g, const void* __restrict__ be, size_t goff,
    float* __restrict__ out, const int* __restrict__ flag, int D)
{
    const int isbf = *flag;
    const int row = blockIdx.x;
    const int t = threadIdx.x;
    float v[4];
    int cnt = 0;
    float s = 0.f;
    for (int i = t; i < D; i += 64) {
        float x = a[(size_t)row*D + i];
        if (b) x += b[(size_t)row*D + i];
        v[cnt++] = x; s += x;
    }
    #pragma unroll
    for (int off = 32; off > 0; off >>= 1) s += __shfl_down(s, off);
    s = __shfl(s, 0);
    const float mean = s / D;
    float qq = 0.f;
    for (int c2 = 0; c2 < cnt; ++c2) { float d = v[c2]-mean; qq += d*d; }
    #pragma unroll
    for (int off = 32; off > 0; off >>= 1) qq += __shfl_down(qq, off);
    qq = __shfl(qq, 0);
    const float inv = rsqrtf(fmaxf(qq, 0.f) / D + 1e-5f);
    cnt = 0;
    for (int i = t; i < D; i += 64)
        out[(size_t)row*D + i] = (v[cnt++] - mean)*inv*ldf(g, goff + i, isbf) + ldf(be, goff + i, isbf);
}

// ---------------- full-graph attention (block-diagonal complete, heads 0..3) ----------------
__global__ __launch_bounds__(128) void full_attn_k(
    const float* __restrict__ q, const float* __restrict__ k, const float* __restrict__ v,
    const void* __restrict__ rel, const int* __restrict__ feat, float* __restrict__ o,
    const int* __restrict__ flag)
{
    __shared__ float ks[kNPB][kED];
    __shared__ float vs[kNPB][kED];
    __shared__ float rs[128][kED+1];
    const int isbf = *flag;
    const int b = blockIdx.x >> 2, h = blockIdx.x & 3;
    const int t = threadIdx.x;
    for (int i = t; i < 128*kED; i += 128) rs[i>>5][i&31] = ldf(rel, i, isbf);
    for (int i = t; i < kNPB*kED; i += 128) {
        int r = i >> 5, d = i & 31;
        size_t base = ((size_t)(b*kNPB + r))*kND + h*kED;
        ks[r][d] = k[base + d];
        vs[r][d] = v[base + d];
    }
    __syncthreads();
    float qr[kED];
    { size_t base = ((size_t)(b*kNPB + t))*kND + h*kED;
      #pragma unroll
      for (int d=0; d<kED; ++d) qr[d] = q[base + d]; }
    const int* fp = feat + (size_t)b*kNPB*kNPB + t;
    float m = -1e30f, l = 0.f;
    float acc[kED];
    #pragma unroll
    for (int d=0; d<kED; ++d) acc[d] = 0.f;
    int f = fp[0];
    for (int s = 0; s < kNPB; ++s) {
        int fn = (s+1 < kNPB) ? fp[(s+1)*kNPB] : 0;
        float sc = 0.f;
        #pragma unroll
        for (int d=0; d<kED; ++d) sc += (ks[s][d] + rs[f][d]) * qr[d];
        sc *= kScaleN;
        float mn = fmaxf(m, sc);
        float c0 = __expf(fminf(m - mn, 0.f));
        float pp = __expf(fminf(sc - mn, 0.f));
        l = l*c0 + pp;
        #pragma unroll
        for (int d=0; d<kED; ++d) acc[d] = acc[d]*c0 + pp*(vs[s][d] + rs[f][d]);
        m = mn;
        f = fn;
    }
    const float inv = 1.f / fmaxf(l, 1e-30f);
    size_t base = ((size_t)(b*kNPB + t))*kND + h*kED;
    #pragma unroll
    for (int d=0; d<kED; ++d) o[base + d] = acc[d]*inv;
}

// ---------------- local-graph scatter attention (heads 4..7) ----------------
__global__ __launch_bounds__(256) void loc_score_k(
    const float* __restrict__ q, const float* __restrict__ k, const float* __restrict__ lg,
    const int* __restrict__ gsrc, const int* __restrict__ gdst,
    float* __restrict__ sc, unsigned* __restrict__ smax)
{
    int g = blockIdx.x*256 + threadIdx.x;   // kEL*4
    int e = g >> 2, h = g & 3;
    int s = gsrc[e], d2 = gdst[e];
    const float* kp = k + (size_t)s*kND + (4+h)*kED;
    const float* qp = q + (size_t)d2*kND + (4+h)*kED;
    const float* ep = lg + (size_t)e*kED;
    float a = 0.f;
    #pragma unroll
    for (int d=0; d<kED; ++d) a += (kp[d] + ep[d]) * qp[d];
    a *= kScaleN;
    sc[g] = a;
    atomicMax(&smax[d2*4 + h], f2o(a));
}
__global__ __launch_bounds__(256) void loc_exp_k(
    const int* __restrict__ gdst, float* __restrict__ sc,
    const unsigned* __restrict__ smax, float* __restrict__ den)
{
    int g = blockIdx.x*256 + threadIdx.x;   // kEL*4
    int e = g >> 2, h = g & 3;
    int d2 = gdst[e];
    float ex = __expf(fminf(sc[g] - o2f(smax[d2*4 + h]), 0.f));
    sc[g] = ex;
    atomicAdd(&den[d2*4 + h], ex);
}
__global__ __launch_bounds__(256) void loc_out_k(
    const float* __restrict__ v, const float* __restrict__ lg,
    const int* __restrict__ gsrc, const int* __restrict__ gdst,
    const float* __restrict__ sc, const float* __restrict__ den,
    float* __restrict__ o)
{
    int g = blockIdx.x*256 + threadIdx.x;   // kEL*128
    int d = g & 31, h = (g>>5)&3, e = g >> 7;
    int s = gsrc[e], d2 = gdst[e];
    float alpha = sc[e*4+h] / fmaxf(den[d2*4+h], 1e-30f);
    float val = alpha * (v[(size_t)s*kND + (4+h)*kED + d] + lg[(size_t)e*kED + d]);
    atomicAdd(&o[(size_t)d2*kND + (4+h)*kED + d], val);
}

// ---------------- line-graph scatter attention (8 heads, d=4, no e-bias) ----------------
__global__ __launch_bounds__(256) void lgs_score_k(
    const float* __restrict__ eq, const float* __restrict__ ek,
    const int* __restrict__ lsrc, const int* __restrict__ ldst,
    float* __restrict__ sc, unsigned* __restrict__ smax)
{
    int g = blockIdx.x*256 + threadIdx.x;   // kELG*8
    int e = g >> 3, h = g & 7;
    int s = lsrc[e], d2 = ldst[e];
    const float* kp = ek + (size_t)s*kED + h*4;
    const float* qp = eq + (size_t)d2*kED + h*4;
    float a = 0.f;
    #pragma unroll
    for (int d=0; d<4; ++d) a += kp[d]*qp[d];
    a *= 0.5f;
    sc[g] = a;
    atomicMax(&smax[d2*8 + h], f2o(a));
}
__global__ __launch_bounds__(256) void lgs_exp_k(
    const int* __restrict__ ldst, float* __restrict__ sc,
    const unsigned* __restrict__ smax, float* __restrict__ den)
{
    int g = blockIdx.x*256 + threadIdx.x;   // kELG*8
    int e = g >> 3, h = g & 7;
    int d2 = ldst[e];
    float ex = __expf(fminf(sc[g] - o2f(smax[d2*8 + h]), 0.f));
    sc[g] = ex;
    atomicAdd(&den[d2*8 + h], ex);
}
__global__ __launch_bounds__(256) void lgs_out_k(
    const float* __restrict__ ev,
    const int* __restrict__ lsrc, const int* __restrict__ ldst,
    const float* __restrict__ sc, const float* __restrict__ den,
    float* __restrict__ ow)
{
    int g = blockIdx.x*256 + threadIdx.x;   // kELG*32
    int d = g & 3, h = (g>>2)&7, e = g >> 5;
    int s = lsrc[e], d2 = ldst[e];
    float alpha = sc[e*8+h] / fmaxf(den[d2*8+h], 1e-30f);
    atomicAdd(&ow[(size_t)d2*kED + h*4 + d], alpha * ev[(size_t)s*kED + h*4 + d]);
}

// ---------------- output ----------------
__global__ void out_k(const float* __restrict__ xf, const float* __restrict__ lgf,
                      void* __restrict__ out, const int* __restrict__ flag){
    const int isbf = *flag;
    int g = blockIdx.x*256 + threadIdx.x;
    float v = (g < kN*kND) ? xf[g] : lgf[g - kN*kND];
    if (isbf) ((bf16*)out)[g] = __float2bfloat16(v);
    else      ((float*)out)[g] = v;
}

// ---------------- host helpers ----------------
static inline void gemm64(const float* A, const int* idx, const void* W, size_t woff,
                          const void* bias, size_t boff, const float* Res, float* C,
                          const int* flag, int M, int N, int K, int flags, hipStream_t s){
    dim3 grid((N+63)/64, M/64);
    gemm_k<64><<<grid, 256, 0, s>>>(A, idx, W, woff, bias, boff, Res, C, flag, M, N, K, flags);
}
static inline void gemm32(const float* A, const int* idx, const void* W, size_t woff,
                          const void* bias, size_t boff, const float* Res, float* C,
                          const int* flag, int M, int N, int K, int flags, hipStream_t s){
    dim3 grid((N+31)/32, M/64);
    gemm_k<32><<<grid, 256, 0, s>>>(A, idx, W, woff, bias, boff, Res, C, flag, M, N, K, flags);
}

extern "C" void kernel_launch(void* const* d_in, const int* in_sizes, int n_in,
                              void* d_out, int out_size, void* d_ws, size_t ws_size,
                              hipStream_t stream) {
    const void* x_in      = d_in[0];
    const void* rel       = d_in[1];
    const int* g_src      = (const int*)d_in[4];
    const int* g_dst      = (const int*)d_in[5];
    const int* lg_src     = (const int*)d_in[6];
    const int* lg_dst     = (const int*)d_in[7];
    const int* edge_feat  = (const int*)d_in[8];
    const int* full_feat  = (const int*)d_in[9];
    const void* n_Wq   = d_in[10];
    const void* n_bq   = d_in[11];
    const void* n_Wk   = d_in[12];
    const void* n_bk   = d_in[13];
    const void* n_Wv   = d_in[14];
    const void* n_bv   = d_in[15];
    const void* n_Wo   = d_in[16];
    const void* n_bo   = d_in[17];
    const void* n_lng  = d_in[18];
    const void* n_lnb  = d_in[19];
    const void* n_fW1  = d_in[20];
    const void* n_fb1  = d_in[21];
    const void* n_fW2  = d_in[22];
    const void* n_fb2  = d_in[23];
    const void* n_flng = d_in[24];
    const void* n_flnb = d_in[25];
    const void* e_Wsrc = d_in[26];
    const void* e_Wdst = d_in[27];
    const void* e_Wq   = d_in[28];
    const void* e_bq   = d_in[29];
    const void* e_Wk   = d_in[30];
    const void* e_Wv   = d_in[31];
    const void* e_Wo   = d_in[32];
    const void* e_bo   = d_in[33];
    const void* e_lng  = d_in[34];
    const void* e_lnb  = d_in[35];
    const void* e_fW1  = d_in[36];
    const void* e_fb1  = d_in[37];
    const void* e_fW2  = d_in[38];
    const void* e_fb2  = d_in[39];
    const void* e_flng = d_in[40];
    const void* e_flnb = d_in[41];

    // ---- workspace carve-up (fp32) ----
    float* p = (float*)d_ws;
    size_t off = 0;
    auto AL = [&](size_t n){ float* r = p + off; off += n; return r; };
    int* flagp = (int*)AL(64);
    float* xA   = AL((size_t)kN*kND);
    float* xB   = AL((size_t)kN*kND);
    float* xM   = AL((size_t)kN*kND);
    float* qb   = AL((size_t)kN*kND);
    float* kb   = AL((size_t)kN*kND);
    float* vb   = AL((size_t)kN*kND);
    float* ob   = AL((size_t)kN*kND);
    float* tN   = AL((size_t)kN*kND);
    float* nh   = AL((size_t)kN*1024);        // node FFN hidden
    float* lgA  = AL((size_t)kEL*kED);
    float* lgB  = AL((size_t)kEL*kED);
    float* lgM  = AL((size_t)kEL*kED);
    float* eqb  = AL((size_t)kEL*kED);
    float* ekb  = AL((size_t)kEL*kED);
    float* evb  = AL((size_t)kEL*kED);
    float* owb  = AL((size_t)kEL*kED);
    float* xs   = AL((size_t)kN*kED);
    float* xd   = AL((size_t)kN*kED);
    float* scL  = AL((size_t)kEL*4);
    unsigned* smL = (unsigned*)AL((size_t)kN*4);
    float* dnL  = AL((size_t)kN*4);
    float* scG  = AL((size_t)kELG*8);
    unsigned* smG = (unsigned*)AL((size_t)kEL*8);
    float* dnG  = AL((size_t)kEL*8);
    if (ws_size < off * sizeof(float)) return;

    detect_k<<<1, 64, 0, stream>>>((const unsigned short*)x_in, flagp);
    cast_x_k<<<(kN*kND)/256, 256, 0, stream>>>(x_in, xA, flagp, kN*kND);
    init_lg_k<<<(kEL*kED)/256, 256, 0, stream>>>(rel, edge_feat, lgA, flagp);

    float* xc = xA;  float* xn = xB;
    float* lgc = lgA; float* lgn = lgB;

    for (int i = 0; i < kL; ++i) {
        const size_t oW   = (size_t)i*kND*kND;
        const size_t ofW1 = (size_t)i*kND*1024;
        const size_t ofW2 = (size_t)i*1024*kND;
        const size_t oWs  = (size_t)i*kND*kED;
        const size_t oeW  = (size_t)i*kED*kED;
        const size_t oefW1= (size_t)i*kED*128;
        const size_t oefW2= (size_t)i*128*kED;
        const size_t o256 = (size_t)i*kND;
        const size_t o1024= (size_t)i*1024;
        const size_t o32  = (size_t)i*kED;
        const size_t o128 = (size_t)i*128;

        // ===== node update =====
        gemm64(xc, nullptr, n_Wq, oW, n_bq, o256, nullptr, qb, flagp, kN, kND, kND, 4, stream);
        gemm64(xc, nullptr, n_Wk, oW, n_bk, o256, nullptr, kb, flagp, kN, kND, kND, 4, stream);
        gemm64(xc, nullptr, n_Wv, oW, n_bv, o256, nullptr, vb, flagp, kN, kND, kND, 4, stream);
        hipMemsetAsync(ob,  0, (size_t)kN*kND*sizeof(float), stream);
        hipMemsetAsync(smL, 0, (size_t)kN*4*sizeof(unsigned), stream);
        hipMemsetAsync(dnL, 0, (size_t)kN*4*sizeof(float), stream);
        full_attn_k<<<128, 128, 0, stream>>>(qb, kb, vb, rel, full_feat, ob, flagp);
        loc_score_k<<<(kEL*4)/256, 256, 0, stream>>>(qb, kb, lgc, g_src, g_dst, scL, smL);
        loc_exp_k  <<<(kEL*4)/256, 256, 0, stream>>>(g_dst, scL, smL, dnL);
        loc_out_k  <<<(kEL*128)/256, 256, 0, stream>>>(vb, lgc, g_src, g_dst, scL, dnL, ob);
        gemm64(ob, nullptr, n_Wo, oW, n_bo, o256, nullptr, tN, flagp, kN, kND, kND, 4, stream);
        ln_k<<<kN, 64, 0, stream>>>(xc, tN, n_lng, n_lnb, o256, xM, flagp, kND);
        gemm64(xM, nullptr, n_fW1, ofW1, n_fb1, o1024, nullptr, nh, flagp, kN, 1024, kND, 4|2, stream);
        gemm64(nh, nullptr, n_fW2, ofW2, n_fb2, o256, nullptr, tN, flagp, kN, kND, 1024, 4, stream);
        ln_k<<<kN, 64, 0, stream>>>(xM, tN, n_flng, n_flnb, o256, xn, flagp, kND);

        // ===== edge update (uses PRE-update xc, lgc) =====
        gemm32(xc, nullptr, e_Wsrc, oWs, nullptr, 0, nullptr, xs, flagp, kN, kED, kND, 0, stream);
        gemm32(xc, nullptr, e_Wdst, oWs, nullptr, 0, nullptr, xd, flagp, kN, kED, kND, 0, stream);
        eqkv_k<<<kEL/64, 256, 0, stream>>>(lgc, xs, xd, g_src, g_dst,
                                           e_Wq, e_Wk, e_Wv, oeW, e_bq, o32,
                                           eqb, ekb, evb, flagp);
        hipMemsetAsync(owb, 0, (size_t)kEL*kED*sizeof(float), stream);
        hipMemsetAsync(smG, 0, (size_t)kEL*8*sizeof(unsigned), stream);
        hipMemsetAsync(dnG, 0, (size_t)kEL*8*sizeof(float), stream);
        lgs_score_k<<<(kELG*8)/256, 256, 0, stream>>>(eqb, ekb, lg_src, lg_dst, scG, smG);
        lgs_exp_k  <<<(kELG*8)/256, 256, 0, stream>>>(lg_dst, scG, smG, dnG);
        lgs_out_k  <<<(kELG*32)/256, 256, 0, stream>>>(evb, lg_src, lg_dst, scG, dnG, owb);
        ewo_ln_k<<<kEL/64, 256, 0, stream>>>(owb, lgc, e_Wo, oeW, e_bo, o32,
                                             e_lng, e_lnb, o32, lgM, flagp);
        effn_ln_k<<<kEL/32, 256, 0, stream>>>(lgM, e_fW1, oefW1, e_fb1, o128,
                                              e_fW2, oefW2, e_fb2, o32,
                                              e_flng, e_flnb, o32, lgn, flagp);

        { float* t = xc; xc = xn; xn = t; }
        { float* t = lgc; lgc = lgn; lgn = t; }
    }

    out_k<<<(kN*kND + kEL*kED)/256, 256, 0, stream>>>(xc, lgc, d_out, flagp);
}